// Round 1
// baseline (412.391 us; speedup 1.0000x reference)
//
#include <hip/hip_runtime.h>

#define N_IMG 9216
#define DFEAT 1024
#define NB 72            // 9216 / 128 tile blocks per dim
#define RPB 8            // rows per block in the MLP kernel
#define EPS 1e-6f

typedef __attribute__((ext_vector_type(8))) short short8;
typedef __attribute__((ext_vector_type(4))) float floatx4;

__device__ __forceinline__ void async_copy16(const void* g, void* l) {
  __builtin_amdgcn_global_load_lds((const __attribute__((address_space(1))) void*)g,
                                   (__attribute__((address_space(3))) void*)l,
                                   16, 0, 0);
}

__device__ __forceinline__ unsigned short f2bf(float x) {
  union { float f; unsigned u; } a; a.f = x;
  unsigned u = a.u;
  u += 0x7fffu + ((u >> 16) & 1u);   // round-to-nearest-even
  return (unsigned short)(u >> 16);
}

// ---- kernel 0: zero the two accumulators (ws is poisoned 0xAA each call) ----
__global__ void init_sums(double* sums) {
  sums[0] = 0.0;   // sum of sim over all N^2 pairs
  sums[1] = 0.0;   // sum of agg over N rows
}

// ---- kernel 1: fp32 -> bf16 rows + fp32 squared norms ----
__global__ __launch_bounds__(256) void convert_rows(const float* __restrict__ f,
                                                    unsigned short* __restrict__ fb,
                                                    float* __restrict__ sq) {
  int row = blockIdx.x;
  int t = threadIdx.x;                       // 256 threads, 4 floats each
  const float4 v = ((const float4*)(f + (size_t)row * DFEAT))[t];
  ushort4 o;
  o.x = f2bf(v.x); o.y = f2bf(v.y); o.z = f2bf(v.z); o.w = f2bf(v.w);
  ((ushort4*)(fb + (size_t)row * DFEAT))[t] = o;
  float s = v.x * v.x + v.y * v.y + v.z * v.z + v.w * v.w;
#pragma unroll
  for (int off = 32; off > 0; off >>= 1) s += __shfl_down(s, off, 64);
  __shared__ float part[4];
  int lane = t & 63, wave = t >> 6;
  if (lane == 0) part[wave] = s;
  __syncthreads();
  if (t == 0) sq[row] = part[0] + part[1] + part[2] + part[3];
}

// ---- kernel 2: fused Gram (bf16 MFMA) + gaussian-sim + global mean reduce ----
// Upper-triangular 128x128 blocks only; off-diagonal weighted x2.
__global__ __launch_bounds__(256) void gram_sim(const unsigned short* __restrict__ fb,
                                                const float* __restrict__ sq,
                                                double* __restrict__ sums) {
  // decode linear idx -> (br, bc) with br <= bc
  int idx = blockIdx.x;
  int br = 0, rem = idx;
  while (rem >= NB - br) { rem -= NB - br; br++; }
  int bc = br + rem;

  __shared__ __align__(16) unsigned short As[128 * 32];  // [row][k] bf16, 8 KB
  __shared__ __align__(16) unsigned short Bs[128 * 32];
  __shared__ float sqA[128], sqB[128];
  __shared__ float wpart[4];

  int t = threadIdx.x;
  int lane = t & 63, wave = t >> 6;

  if (t < 128) sqA[t] = sq[br * 128 + t];
  else         sqB[t - 128] = sq[bc * 128 + (t - 128)];

  floatx4 acc[4][4];
#pragma unroll
  for (int i = 0; i < 4; i++)
#pragma unroll
    for (int j = 0; j < 4; j++)
      acc[i][j] = (floatx4){0.f, 0.f, 0.f, 0.f};

  const int wr = (wave & 1) * 64;     // wave's 64x64 subtile
  const int wc = (wave >> 1) * 64;

  const unsigned short* Abase = fb + (size_t)br * 128 * DFEAT;
  const unsigned short* Bbase = fb + (size_t)bc * 128 * DFEAT;

  // staging coords: chunk c covers 16 B; row = c>>2 (rows are 32 bf16 = 64 B)
  const int c0 = t, c1 = t + 256;
  const int r0 = c0 >> 2, ci0 = (c0 & 3) * 8;
  const int r1 = c1 >> 2, ci1 = (c1 & 3) * 8;

  for (int k0 = 0; k0 < DFEAT; k0 += 32) {
    __syncthreads();   // previous iter's ds_reads done before overwrite
    async_copy16(Abase + (size_t)r0 * DFEAT + k0 + ci0, &As[c0 * 8]);
    async_copy16(Abase + (size_t)r1 * DFEAT + k0 + ci1, &As[c1 * 8]);
    async_copy16(Bbase + (size_t)r0 * DFEAT + k0 + ci0, &Bs[c0 * 8]);
    async_copy16(Bbase + (size_t)r1 * DFEAT + k0 + ci1, &Bs[c1 * 8]);
    __syncthreads();   // vmcnt(0) drain: LDS writes visible

    short8 a[4], b[4];
    const int mrow = lane & 15, kq = (lane >> 4) * 8;
#pragma unroll
    for (int mt = 0; mt < 4; mt++)
      a[mt] = *(const short8*)&As[(wr + mt * 16 + mrow) * 32 + kq];
#pragma unroll
    for (int nt = 0; nt < 4; nt++)
      b[nt] = *(const short8*)&Bs[(wc + nt * 16 + mrow) * 32 + kq];
#pragma unroll
    for (int mt = 0; mt < 4; mt++)
#pragma unroll
      for (int nt = 0; nt < 4; nt++)
        acc[mt][nt] = __builtin_amdgcn_mfma_f32_16x16x32_bf16(a[mt], b[nt], acc[mt][nt], 0, 0, 0);
  }

  // epilogue: C/D layout col=lane&15, row=(lane>>4)*4+reg
  float lsum = 0.f;
  const int rq = (lane >> 4) * 4, cn = lane & 15;
  const bool diag = (br == bc);
#pragma unroll
  for (int mt = 0; mt < 4; mt++) {
#pragma unroll
    for (int nt = 0; nt < 4; nt++) {
#pragma unroll
      for (int r = 0; r < 4; r++) {
        int i_loc = wr + mt * 16 + rq + r;
        int j_loc = wc + nt * 16 + cn;
        float g  = acc[mt][nt][r];
        float si = sqA[i_loc], sj = sqB[j_loc];
        float cosv = g / fmaxf(sqrtf(si * sj), EPS);
        float d2   = fmaxf(si + sj - 2.f * g, 0.f);
        float den  = fmaxf(1024.f * (1.f + cosv), EPS);
        float sim  = __expf(-d2 / den);
        if (diag && i_loc == j_loc) sim = 1.f;
        lsum += sim;
      }
    }
  }
#pragma unroll
  for (int off = 32; off > 0; off >>= 1) lsum += __shfl_down(lsum, off, 64);
  if (lane == 0) wpart[wave] = lsum;
  __syncthreads();
  if (t == 0) {
    float tot = (wpart[0] + wpart[1] + wpart[2] + wpart[3]) * (diag ? 1.f : 2.f);
    atomicAdd(&sums[0], (double)tot);
  }
}

// ---- kernel 3: fused 3-layer MLP (fp32) + sigmoid + mean accumulate ----
__global__ __launch_bounds__(128) void mlp_agg(const float* __restrict__ f,
                                               const float* __restrict__ scores,
                                               const float* __restrict__ W1, const float* __restrict__ b1,
                                               const float* __restrict__ g1, const float* __restrict__ be1,
                                               const float* __restrict__ W2, const float* __restrict__ b2,
                                               const float* __restrict__ g2, const float* __restrict__ be2,
                                               const float* __restrict__ W3, const float* __restrict__ b3,
                                               double* __restrict__ sums) {
  __shared__ float xs[RPB][DFEAT + 1];
  __shared__ float h1s[RPB][128];
  __shared__ float h2s[RPB][64];
  int t = threadIdx.x;                 // 128 threads
  int r0 = blockIdx.x * RPB;
  for (int r = 0; r < RPB; r++) {
    const float* src = f + (size_t)(r0 + r) * DFEAT;
    for (int k = t; k < DFEAT; k += 128) xs[r][k] = src[k];
  }
  if (t < RPB) xs[t][DFEAT] = scores[r0 + t];
  __syncthreads();

  const float inv = 1.0f / sqrtf(1.0f + 1e-5f);   // BN eval scale

  // layer 1: 1025 -> 128, thread t owns output feature t
  float acc[RPB];
#pragma unroll
  for (int r = 0; r < RPB; r++) acc[r] = 0.f;
  for (int k = 0; k < DFEAT + 1; k++) {
    float w = W1[k * 128 + t];
#pragma unroll
    for (int r = 0; r < RPB; r++) acc[r] += xs[r][k] * w;
  }
  {
    float sc = g1[t] * inv, bi = b1[t], be = be1[t];
#pragma unroll
    for (int r = 0; r < RPB; r++)
      h1s[r][t] = fmaxf(sc * (acc[r] + bi) + be, 0.f);
  }
  __syncthreads();

  // layer 2: 128 -> 64, thread (j = t&63) for rows rh..rh+3
  {
    int j = t & 63, rh = (t >> 6) * 4;
    float a2[4] = {0.f, 0.f, 0.f, 0.f};
    for (int k = 0; k < 128; k++) {
      float w = W2[k * 64 + j];
#pragma unroll
      for (int rr = 0; rr < 4; rr++) a2[rr] += h1s[rh + rr][k] * w;
    }
    float sc = g2[j] * inv, bi = b2[j], be = be2[j];
#pragma unroll
    for (int rr = 0; rr < 4; rr++)
      h2s[rh + rr][j] = fmaxf(sc * (a2[rr] + bi) + be, 0.f);
  }
  __syncthreads();

  // layer 3: 64 -> 1 + sigmoid, one thread per row
  if (t < RPB) {
    float z = b3[0];
    for (int k = 0; k < 64; k++) z += h2s[t][k] * W3[k];
    float s = 1.f / (1.f + __expf(-z));
    atomicAdd(&sums[1], (double)s);
  }
}

// ---- kernel 4: combine ----
__global__ void finalize(const double* __restrict__ sums, float* __restrict__ out) {
  double simmean = sums[0] / ((double)N_IMG * (double)N_IMG);
  double aggmean = sums[1] / (double)N_IMG;
  out[0] = (float)(aggmean * simmean);
}

extern "C" void kernel_launch(void* const* d_in, const int* in_sizes, int n_in,
                              void* d_out, int out_size, void* d_ws, size_t ws_size,
                              hipStream_t stream) {
  const float* f      = (const float*)d_in[0];
  const float* scores = (const float*)d_in[1];
  const float* W1 = (const float*)d_in[2];
  const float* b1 = (const float*)d_in[3];
  const float* g1 = (const float*)d_in[4];
  const float* be1 = (const float*)d_in[5];
  const float* W2 = (const float*)d_in[6];
  const float* b2 = (const float*)d_in[7];
  const float* g2 = (const float*)d_in[8];
  const float* be2 = (const float*)d_in[9];
  const float* W3 = (const float*)d_in[10];
  const float* b3 = (const float*)d_in[11];

  // workspace layout: bf16 features (18.87 MB) | sq (36 KB) | sums (16 B)
  unsigned short* fb = (unsigned short*)d_ws;
  float* sq    = (float*)((char*)d_ws + (size_t)N_IMG * DFEAT * 2);
  double* sums = (double*)((char*)d_ws + (size_t)N_IMG * DFEAT * 2 + (size_t)N_IMG * 4);

  init_sums<<<1, 1, 0, stream>>>(sums);
  convert_rows<<<N_IMG, 256, 0, stream>>>(f, fb, sq);
  mlp_agg<<<N_IMG / RPB, 128, 0, stream>>>(f, scores, W1, b1, g1, be1,
                                           W2, b2, g2, be2, W3, b3, sums);
  gram_sim<<<NB * (NB + 1) / 2, 256, 0, stream>>>(fb, sq, sums);
  finalize<<<1, 1, 0, stream>>>(sums, (float*)d_out);
}

// Round 2
// 260.987 us; speedup vs baseline: 1.5801x; 1.5801x over previous
//
#include <hip/hip_runtime.h>

#define N_IMG 9216
#define DFEAT 1024
#define NB 72            // 9216 / 128 tile blocks per dim
#define EPS 1e-6f

typedef __attribute__((ext_vector_type(8))) short short8;
typedef __attribute__((ext_vector_type(4))) float floatx4;

__device__ __forceinline__ void async_copy16(const void* g, void* l) {
  __builtin_amdgcn_global_load_lds((const __attribute__((address_space(1))) void*)g,
                                   (__attribute__((address_space(3))) void*)l,
                                   16, 0, 0);
}

__device__ __forceinline__ unsigned short f2bf(float x) {
  union { float f; unsigned u; } a; a.f = x;
  unsigned u = a.u;
  u += 0x7fffu + ((u >> 16) & 1u);   // round-to-nearest-even
  return (unsigned short)(u >> 16);
}

// ---- kernel 1: fp32 -> bf16 rows + squared norms + inverse norms ----
__global__ __launch_bounds__(256) void convert_rows(const float* __restrict__ f,
                                                    unsigned short* __restrict__ fb,
                                                    float* __restrict__ sq,
                                                    float* __restrict__ rn) {
  int row = blockIdx.x;
  int t = threadIdx.x;                       // 256 threads, 4 floats each
  const float4 v = ((const float4*)(f + (size_t)row * DFEAT))[t];
  ushort4 o;
  o.x = f2bf(v.x); o.y = f2bf(v.y); o.z = f2bf(v.z); o.w = f2bf(v.w);
  ((ushort4*)(fb + (size_t)row * DFEAT))[t] = o;
  float s = v.x * v.x + v.y * v.y + v.z * v.z + v.w * v.w;
#pragma unroll
  for (int off = 32; off > 0; off >>= 1) s += __shfl_down(s, off, 64);
  __shared__ float part[4];
  int lane = t & 63, wave = t >> 6;
  if (lane == 0) part[wave] = s;
  __syncthreads();
  if (t == 0) {
    float tot = part[0] + part[1] + part[2] + part[3];
    sq[row] = tot;
    rn[row] = rsqrtf(tot);
  }
}

// ---- kernel 1b: transpose W1[0:1024][128] -> bf16 W1t[128][1024]; init sums ----
__global__ __launch_bounds__(256) void prep_w1t(const float* __restrict__ W1,
                                                unsigned short* __restrict__ W1t,
                                                double* __restrict__ sums) {
  int j = blockIdx.x;          // 128 blocks, one output feature each
  int t = threadIdx.x;
  if (j == 0 && t < 2) sums[t] = 0.0;
#pragma unroll
  for (int k = t; k < DFEAT; k += 256)
    W1t[(size_t)j * DFEAT + k] = f2bf(W1[(size_t)k * 128 + j]);
}

// ---- kernel 2: fused Gram (bf16 MFMA) + gaussian-sim + global mean reduce ----
// Upper-triangular 128x128 blocks only; off-diagonal weighted x2.
__global__ __launch_bounds__(256) void gram_sim(const unsigned short* __restrict__ fb,
                                                const float* __restrict__ sq,
                                                const float* __restrict__ rn,
                                                double* __restrict__ sums) {
  int idx = blockIdx.x;
  int br = 0, rem = idx;
  while (rem >= NB - br) { rem -= NB - br; br++; }
  int bc = br + rem;

  __shared__ __align__(16) unsigned short As[128 * 32];  // 8 KB
  __shared__ __align__(16) unsigned short Bs[128 * 32];
  __shared__ float sqA[128], sqB[128], rnA[128], rnB[128];
  __shared__ float wpart[4];

  int t = threadIdx.x;
  int lane = t & 63, wave = t >> 6;

  if (t < 128) { sqA[t] = sq[br * 128 + t]; rnA[t] = rn[br * 128 + t]; }
  else { sqB[t - 128] = sq[bc * 128 + (t - 128)]; rnB[t - 128] = rn[bc * 128 + (t - 128)]; }

  floatx4 acc[4][4];
#pragma unroll
  for (int i = 0; i < 4; i++)
#pragma unroll
    for (int j = 0; j < 4; j++)
      acc[i][j] = (floatx4){0.f, 0.f, 0.f, 0.f};

  const int wr = (wave & 1) * 64;
  const int wc = (wave >> 1) * 64;

  const unsigned short* Abase = fb + (size_t)br * 128 * DFEAT;
  const unsigned short* Bbase = fb + (size_t)bc * 128 * DFEAT;

  const int c0 = t, c1 = t + 256;
  const int r0 = c0 >> 2, ci0 = (c0 & 3) * 8;
  const int r1 = c1 >> 2, ci1 = (c1 & 3) * 8;

  for (int k0 = 0; k0 < DFEAT; k0 += 32) {
    __syncthreads();
    async_copy16(Abase + (size_t)r0 * DFEAT + k0 + ci0, &As[c0 * 8]);
    async_copy16(Abase + (size_t)r1 * DFEAT + k0 + ci1, &As[c1 * 8]);
    async_copy16(Bbase + (size_t)r0 * DFEAT + k0 + ci0, &Bs[c0 * 8]);
    async_copy16(Bbase + (size_t)r1 * DFEAT + k0 + ci1, &Bs[c1 * 8]);
    __syncthreads();

    short8 a[4], b[4];
    const int mrow = lane & 15, kq = (lane >> 4) * 8;
#pragma unroll
    for (int mt = 0; mt < 4; mt++)
      a[mt] = *(const short8*)&As[(wr + mt * 16 + mrow) * 32 + kq];
#pragma unroll
    for (int nt = 0; nt < 4; nt++)
      b[nt] = *(const short8*)&Bs[(wc + nt * 16 + mrow) * 32 + kq];
#pragma unroll
    for (int mt = 0; mt < 4; mt++)
#pragma unroll
      for (int nt = 0; nt < 4; nt++)
        acc[mt][nt] = __builtin_amdgcn_mfma_f32_16x16x32_bf16(a[mt], b[nt], acc[mt][nt], 0, 0, 0);
  }

  // epilogue: C/D layout col=lane&15, row=(lane>>4)*4+reg
  const int rq = (lane >> 4) * 4, cn = lane & 15;
  const bool diag = (br == bc);
  float siv[16], rniv[16], sjv[4], rnjv[4];
#pragma unroll
  for (int mt = 0; mt < 4; mt++)
#pragma unroll
    for (int r = 0; r < 4; r++) {
      siv[mt * 4 + r] = sqA[wr + mt * 16 + rq + r];
      rniv[mt * 4 + r] = rnA[wr + mt * 16 + rq + r];
    }
#pragma unroll
  for (int nt = 0; nt < 4; nt++) {
    sjv[nt] = sqB[wc + nt * 16 + cn];
    rnjv[nt] = rnB[wc + nt * 16 + cn];
  }

  float lsum = 0.f;
#pragma unroll
  for (int mt = 0; mt < 4; mt++) {
#pragma unroll
    for (int nt = 0; nt < 4; nt++) {
#pragma unroll
      for (int r = 0; r < 4; r++) {
        float g = acc[mt][nt][r];
        float cosv = g * rniv[mt * 4 + r] * rnjv[nt];
        float den = fmaf(1024.f, cosv, 1024.f);       // never near 0 on this data
        float d2 = siv[mt * 4 + r] + sjv[nt] - (g + g);
        float arg = -d2 * __builtin_amdgcn_rcpf(den);
        float sim = __builtin_amdgcn_exp2f(arg * 1.44269504f);
        if (diag && (wr + mt * 16 + rq + r) == (wc + nt * 16 + cn)) sim = 1.f;
        lsum += sim;
      }
    }
  }
#pragma unroll
  for (int off = 32; off > 0; off >>= 1) lsum += __shfl_down(lsum, off, 64);
  if (lane == 0) wpart[wave] = lsum;
  __syncthreads();
  if (t == 0) {
    float tot = (wpart[0] + wpart[1] + wpart[2] + wpart[3]) * (diag ? 1.f : 2.f);
    atomicAdd(&sums[0], (double)tot);
  }
}

// ---- kernel 3a: layer-1 GEMM via MFMA: h1 = relu(BN(fb @ W1t^T + score*wlast + b1)) ----
__global__ __launch_bounds__(256) void mlp_gemm(const unsigned short* __restrict__ fb,
                                                const unsigned short* __restrict__ W1t,
                                                const float* __restrict__ scores,
                                                const float* __restrict__ W1,
                                                const float* __restrict__ b1,
                                                const float* __restrict__ g1,
                                                const float* __restrict__ be1,
                                                float* __restrict__ h1) {
  int br = blockIdx.x;   // 72 M-tiles of 128 rows; N = 128 (all of it)

  __shared__ __align__(16) unsigned short As[128 * 32];
  __shared__ __align__(16) unsigned short Bs[128 * 32];
  __shared__ float sc[128], b1s[128], g1s[128], be1s[128], wls[128];

  int t = threadIdx.x;
  int lane = t & 63, wave = t >> 6;

  if (t < 128) {
    sc[t] = scores[br * 128 + t];
    b1s[t] = b1[t];
    g1s[t] = g1[t];
    be1s[t] = be1[t];
    wls[t] = W1[(size_t)DFEAT * 128 + t];   // last row of W1 (score weights)
  }

  floatx4 acc[4][4];
#pragma unroll
  for (int i = 0; i < 4; i++)
#pragma unroll
    for (int j = 0; j < 4; j++)
      acc[i][j] = (floatx4){0.f, 0.f, 0.f, 0.f};

  const int wr = (wave & 1) * 64;
  const int wc = (wave >> 1) * 64;

  const unsigned short* Abase = fb + (size_t)br * 128 * DFEAT;
  const unsigned short* Bbase = W1t;   // [128][1024], row j = output feature

  const int c0 = t, c1 = t + 256;
  const int r0 = c0 >> 2, ci0 = (c0 & 3) * 8;
  const int r1 = c1 >> 2, ci1 = (c1 & 3) * 8;

  for (int k0 = 0; k0 < DFEAT; k0 += 32) {
    __syncthreads();
    async_copy16(Abase + (size_t)r0 * DFEAT + k0 + ci0, &As[c0 * 8]);
    async_copy16(Abase + (size_t)r1 * DFEAT + k0 + ci1, &As[c1 * 8]);
    async_copy16(Bbase + (size_t)r0 * DFEAT + k0 + ci0, &Bs[c0 * 8]);
    async_copy16(Bbase + (size_t)r1 * DFEAT + k0 + ci1, &Bs[c1 * 8]);
    __syncthreads();

    short8 a[4], b[4];
    const int mrow = lane & 15, kq = (lane >> 4) * 8;
#pragma unroll
    for (int mt = 0; mt < 4; mt++)
      a[mt] = *(const short8*)&As[(wr + mt * 16 + mrow) * 32 + kq];
#pragma unroll
    for (int nt = 0; nt < 4; nt++)
      b[nt] = *(const short8*)&Bs[(wc + nt * 16 + mrow) * 32 + kq];
#pragma unroll
    for (int mt = 0; mt < 4; mt++)
#pragma unroll
      for (int nt = 0; nt < 4; nt++)
        acc[mt][nt] = __builtin_amdgcn_mfma_f32_16x16x32_bf16(a[mt], b[nt], acc[mt][nt], 0, 0, 0);
  }

  const float inv = 1.0f / sqrtf(1.0f + 1e-5f);
  const int rq = (lane >> 4) * 4, cn = lane & 15;
#pragma unroll
  for (int nt = 0; nt < 4; nt++) {
    int j = wc + nt * 16 + cn;
    float bj = b1s[j], gj = g1s[j] * inv, bej = be1s[j], wj = wls[j];
#pragma unroll
    for (int mt = 0; mt < 4; mt++) {
#pragma unroll
      for (int r = 0; r < 4; r++) {
        int i_loc = wr + mt * 16 + rq + r;
        int row = br * 128 + i_loc;
        float pre = acc[mt][nt][r] + sc[i_loc] * wj + bj;
        float val = fmaxf(gj * pre + bej, 0.f);
        h1[(size_t)row * 128 + j] = val;
      }
    }
  }
}

// ---- kernel 3b: layers 2+3 (fp32) + sigmoid + mean accumulate ----
__global__ __launch_bounds__(256) void mlp_tail(const float* __restrict__ h1,
                                                const float* __restrict__ W2, const float* __restrict__ b2,
                                                const float* __restrict__ g2, const float* __restrict__ be2,
                                                const float* __restrict__ W3, const float* __restrict__ b3,
                                                double* __restrict__ sums) {
  __shared__ float h1s[16][128];
  __shared__ float h2s[16][64];
  __shared__ float ls[16];
  int t = threadIdx.x;                 // 256 threads, 16 rows/block
  int r0 = blockIdx.x * 16;

  // load 16x128 h1 tile, coalesced float4
  {
    const float4* src = (const float4*)(h1 + (size_t)r0 * 128);
    float4* dst = (float4*)&h1s[0][0];
    dst[t] = src[t];
    dst[t + 256] = src[t + 256];
  }
  __syncthreads();

  const float inv = 1.0f / sqrtf(1.0f + 1e-5f);

  // layer 2: 128 -> 64. j = t&63, row group = (t>>6)*4
  {
    int j = t & 63, rh = (t >> 6) * 4;
    float a2[4] = {0.f, 0.f, 0.f, 0.f};
    for (int k = 0; k < 128; k++) {
      float w = W2[k * 64 + j];
#pragma unroll
      for (int rr = 0; rr < 4; rr++) a2[rr] += h1s[rh + rr][k] * w;
    }
    float scv = g2[j] * inv, bi = b2[j], be = be2[j];
#pragma unroll
    for (int rr = 0; rr < 4; rr++)
      h2s[rh + rr][j] = fmaxf(scv * (a2[rr] + bi) + be, 0.f);
  }
  __syncthreads();

  // layer 3: 64 -> 1 + sigmoid
  if (t < 16) {
    float z = b3[0];
    for (int k = 0; k < 64; k++) z += h2s[t][k] * W3[k];
    ls[t] = 1.f / (1.f + __expf(-z));
  }
  __syncthreads();
  if (t == 0) {
    float s = 0.f;
#pragma unroll
    for (int i = 0; i < 16; i++) s += ls[i];
    atomicAdd(&sums[1], (double)s);
  }
}

// ---- kernel 4: combine ----
__global__ void finalize(const double* __restrict__ sums, float* __restrict__ out) {
  double simmean = sums[0] / ((double)N_IMG * (double)N_IMG);
  double aggmean = sums[1] / (double)N_IMG;
  out[0] = (float)(aggmean * simmean);
}

extern "C" void kernel_launch(void* const* d_in, const int* in_sizes, int n_in,
                              void* d_out, int out_size, void* d_ws, size_t ws_size,
                              hipStream_t stream) {
  const float* f      = (const float*)d_in[0];
  const float* scores = (const float*)d_in[1];
  const float* W1 = (const float*)d_in[2];
  const float* b1 = (const float*)d_in[3];
  const float* g1 = (const float*)d_in[4];
  const float* be1 = (const float*)d_in[5];
  const float* W2 = (const float*)d_in[6];
  const float* b2 = (const float*)d_in[7];
  const float* g2 = (const float*)d_in[8];
  const float* be2 = (const float*)d_in[9];
  const float* W3 = (const float*)d_in[10];
  const float* b3 = (const float*)d_in[11];

  // workspace layout
  char* ws = (char*)d_ws;
  unsigned short* fb  = (unsigned short*)ws;                 // 18,874,368 B
  float* sq           = (float*)(ws + 18874368);             // 36,864 B
  float* rn           = (float*)(ws + 18911232);             // 36,864 B
  unsigned short* W1t = (unsigned short*)(ws + 18948096);    // 262,144 B
  float* h1           = (float*)(ws + 19210240);             // 4,718,592 B
  double* sums        = (double*)(ws + 23928832);            // 16 B

  prep_w1t<<<128, 256, 0, stream>>>(W1, W1t, sums);
  convert_rows<<<N_IMG, 256, 0, stream>>>(f, fb, sq, rn);
  mlp_gemm<<<NB, 256, 0, stream>>>(fb, W1t, scores, W1, b1, g1, be1, h1);
  mlp_tail<<<N_IMG / 16, 256, 0, stream>>>(h1, W2, b2, g2, be2, W3, b3, sums);
  gram_sim<<<NB * (NB + 1) / 2, 256, 0, stream>>>(fb, sq, rn, sums);
  finalize<<<1, 1, 0, stream>>>(sums, (float*)d_out);
}

// Round 3
// 232.919 us; speedup vs baseline: 1.7705x; 1.1205x over previous
//
#include <hip/hip_runtime.h>

#define N_IMG 9216
#define DFEAT 1024
#define NB 72            // 9216 / 128 tile blocks per dim

typedef __attribute__((ext_vector_type(8))) short short8;
typedef __attribute__((ext_vector_type(4))) float floatx4;
typedef __attribute__((ext_vector_type(16))) float floatx16;
typedef __attribute__((ext_vector_type(4))) int intx4;
typedef __attribute__((ext_vector_type(8))) int intx8;

__device__ __forceinline__ void async_copy16(const void* g, void* l) {
  __builtin_amdgcn_global_load_lds((const __attribute__((address_space(1))) void*)g,
                                   (__attribute__((address_space(3))) void*)l,
                                   16, 0, 0);
}

__device__ __forceinline__ unsigned short f2bf(float x) {
  union { float f; unsigned u; } a; a.f = x;
  unsigned u = a.u;
  u += 0x7fffu + ((u >> 16) & 1u);   // round-to-nearest-even
  return (unsigned short)(u >> 16);
}

// ---- kernel 1: fp32 -> fp8(e4m3) rows + squared norms + inverse norms ----
__global__ __launch_bounds__(256) void convert_rows(const float* __restrict__ f,
                                                    unsigned char* __restrict__ fb8,
                                                    float* __restrict__ sq,
                                                    float* __restrict__ rn) {
  int row = blockIdx.x;
  int t = threadIdx.x;                       // 256 threads, 4 floats each
  const float4 v = ((const float4*)(f + (size_t)row * DFEAT))[t];
  int pk = __builtin_amdgcn_cvt_pk_fp8_f32(v.x, v.y, 0, false);
  pk = __builtin_amdgcn_cvt_pk_fp8_f32(v.z, v.w, pk, true);
  ((int*)(fb8 + (size_t)row * DFEAT))[t] = pk;
  float s = v.x * v.x + v.y * v.y + v.z * v.z + v.w * v.w;
#pragma unroll
  for (int off = 32; off > 0; off >>= 1) s += __shfl_down(s, off, 64);
  __shared__ float part[4];
  int lane = t & 63, wave = t >> 6;
  if (lane == 0) part[wave] = s;
  __syncthreads();
  if (t == 0) {
    float tot = part[0] + part[1] + part[2] + part[3];
    sq[row] = tot;
    rn[row] = rsqrtf(tot);
  }
}

// ---- kernel 1b: transpose W1[0:1024][128] -> bf16 W1t[128][1024]; init sums ----
__global__ __launch_bounds__(256) void prep_w1t(const float* __restrict__ W1,
                                                unsigned short* __restrict__ W1t,
                                                double* __restrict__ sums) {
  int j = blockIdx.x;          // 128 blocks, one output feature each
  int t = threadIdx.x;
  if (j == 0 && t < 2) sums[t] = 0.0;
#pragma unroll
  for (int k = t; k < DFEAT; k += 256)
    W1t[(size_t)j * DFEAT + k] = f2bf(W1[(size_t)k * 128 + j]);
}

// read one lane's 32-byte f8f6f4 A/B fragment from XOR-swizzled LDS
__device__ __forceinline__ intx8 read_frag8(const unsigned char* base, int row, int kh) {
  int sw = (row >> 1) & 3;
  const intx4 lo = *(const intx4*)(base + row * 64 + (((kh << 1)    ) ^ sw) * 16);
  const intx4 hi = *(const intx4*)(base + row * 64 + (((kh << 1) | 1) ^ sw) * 16);
  intx8 r;
  r[0] = lo[0]; r[1] = lo[1]; r[2] = lo[2]; r[3] = lo[3];
  r[4] = hi[0]; r[5] = hi[1]; r[6] = hi[2]; r[7] = hi[3];
  return r;
}

// ---- kernel 2: fused Gram (MX-fp8 MFMA, K=64/iter) + gaussian-sim + mean reduce ----
// Upper-triangular 128x128 blocks; off-diagonal weighted x2. All MX scales = 1.0.
__global__ __launch_bounds__(256) void gram_sim(const unsigned char* __restrict__ fb8,
                                                const float* __restrict__ sq,
                                                const float* __restrict__ rn,
                                                double* __restrict__ sums) {
  int idx = blockIdx.x;
  int br = 0, rem = idx;
  while (rem >= NB - br) { rem -= NB - br; br++; }
  int bc = br + rem;

  __shared__ __align__(16) unsigned char As8[128 * 64];  // 8 KB, swizzled
  __shared__ __align__(16) unsigned char Bs8[128 * 64];
  __shared__ float sqA[128], sqB[128], rnA[128], rnB[128];
  __shared__ float wpart[4];

  int t = threadIdx.x;
  int lane = t & 63, wave = t >> 6;

  if (t < 128) { sqA[t] = sq[br * 128 + t]; rnA[t] = rn[br * 128 + t]; }
  else { sqB[t - 128] = sq[bc * 128 + (t - 128)]; rnB[t - 128] = rn[bc * 128 + (t - 128)]; }

  floatx16 acc[2][2];
#pragma unroll
  for (int i = 0; i < 2; i++)
#pragma unroll
    for (int j = 0; j < 2; j++)
#pragma unroll
      for (int e = 0; e < 16; e++) acc[i][j][e] = 0.f;

  const int wr = (wave & 1) * 64;     // wave's 64x64 subtile
  const int wc = (wave >> 1) * 64;

  const unsigned char* Abase = fb8 + (size_t)br * 128 * DFEAT;
  const unsigned char* Bbase = fb8 + (size_t)bc * 128 * DFEAT;

  // staging: 512 16B-chunks per matrix, 2 per thread. physical chunk p holds
  // logical col (p&3) ^ ((row>>1)&3)  (rows are 64 B = 4 chunks)
  const int row0 = t >> 2;                       // [0,64)
  const int col0 = (t & 3) ^ ((row0 >> 1) & 3);  // rows 64 apart share swizzle
  const size_t srcOffA = (size_t)row0 * DFEAT + col0 * 16;

  const int r = lane & 31, kh = lane >> 5;

  for (int k0 = 0; k0 < DFEAT; k0 += 64) {
    __syncthreads();
    async_copy16(Abase + srcOffA + k0, &As8[t * 16]);
    async_copy16(Abase + srcOffA + 64 * DFEAT + k0, &As8[(t + 256) * 16]);
    async_copy16(Bbase + srcOffA + k0, &Bs8[t * 16]);
    async_copy16(Bbase + srcOffA + 64 * DFEAT + k0, &Bs8[(t + 256) * 16]);
    __syncthreads();

    intx8 a[2], b[2];
#pragma unroll
    for (int mi = 0; mi < 2; mi++) a[mi] = read_frag8(As8, wr + mi * 32 + r, kh);
#pragma unroll
    for (int ni = 0; ni < 2; ni++) b[ni] = read_frag8(Bs8, wc + ni * 32 + r, kh);
#pragma unroll
    for (int mi = 0; mi < 2; mi++)
#pragma unroll
      for (int ni = 0; ni < 2; ni++)
        acc[mi][ni] = __builtin_amdgcn_mfma_scale_f32_32x32x64_f8f6f4(
            a[mi], b[ni], acc[mi][ni], 0, 0,       // fmtA=fp8, fmtB=fp8
            0, 0x7F7F7F7F, 0, 0x7F7F7F7F);         // scales = 1.0
  }

  // epilogue: C/D 32x32 layout col=lane&31, row=(reg&3)+8*(reg>>2)+4*(lane>>5)
  const bool diag = (br == bc);
  const int coln = lane & 31;
  float lsum = 0.f;
#pragma unroll
  for (int ni = 0; ni < 2; ni++) {
    int j_loc = wc + ni * 32 + coln;
    float sj = sqB[j_loc], rnj = rnB[j_loc];
#pragma unroll
    for (int mi = 0; mi < 2; mi++) {
      int rbase = wr + mi * 32 + 4 * kh;
#pragma unroll
      for (int reg = 0; reg < 16; reg++) {
        int i_loc = rbase + (reg & 3) + 8 * (reg >> 2);
        float g = acc[mi][ni][reg];
        float si = sqA[i_loc], rni = rnA[i_loc];
        float cosv = g * rni * rnj;
        float den = fmaf(1024.f, cosv, 1024.f);    // never near 0 on this data
        float d2 = si + sj - (g + g);
        float arg = -d2 * __builtin_amdgcn_rcpf(den);
        float sim = __builtin_amdgcn_exp2f(arg * 1.44269504f);
        if (diag && i_loc == j_loc) sim = 1.f;
        lsum += sim;
      }
    }
  }
#pragma unroll
  for (int off = 32; off > 0; off >>= 1) lsum += __shfl_down(lsum, off, 64);
  if (lane == 0) wpart[wave] = lsum;
  __syncthreads();
  if (t == 0) {
    float tot = (wpart[0] + wpart[1] + wpart[2] + wpart[3]) * (diag ? 1.f : 2.f);
    atomicAdd(&sums[0], (double)tot);
  }
}

// ---- kernel 3: full MLP per 128-row block: L1 via bf16 MFMA, L2/L3 fp32 in LDS ----
__global__ __launch_bounds__(256) void mlp_full(const float* __restrict__ f,
                                                const unsigned short* __restrict__ W1t,
                                                const float* __restrict__ scores,
                                                const float* __restrict__ W1,
                                                const float* __restrict__ b1,
                                                const float* __restrict__ g1,
                                                const float* __restrict__ be1,
                                                const float* __restrict__ W2, const float* __restrict__ b2,
                                                const float* __restrict__ g2, const float* __restrict__ be2,
                                                const float* __restrict__ W3, const float* __restrict__ b3,
                                                double* __restrict__ sums) {
  int br = blockIdx.x;   // 72 blocks of 128 rows

  __shared__ __align__(16) float As32[128 * 32];        // fp32 A staging, 16 KB
  __shared__ __align__(16) unsigned short Bs[128 * 32]; // bf16 W1t staging, 8 KB
  __shared__ float h1s[128][128];                       // 64 KB
  __shared__ float h2s[128][65];                        // 33.3 KB (padded)
  __shared__ float sc[128], b1s[128], g1s[128], be1s[128], wls[128], ls[128];

  int t = threadIdx.x;
  int lane = t & 63, wave = t >> 6;

  if (t < 128) {
    sc[t] = scores[br * 128 + t];
    b1s[t] = b1[t];
    g1s[t] = g1[t];
    be1s[t] = be1[t];
    wls[t] = W1[(size_t)DFEAT * 128 + t];   // last row of W1 (score weights)
  }

  floatx4 acc[4][4];
#pragma unroll
  for (int i = 0; i < 4; i++)
#pragma unroll
    for (int j = 0; j < 4; j++)
      acc[i][j] = (floatx4){0.f, 0.f, 0.f, 0.f};

  const int wr = (wave & 1) * 64;
  const int wc = (wave >> 1) * 64;

  const float* Abase = f + (size_t)br * 128 * DFEAT;

  // A: 1024 chunks of 16B (4 floats); rows 128B = 8 chunks. 4 chunks/thread.
  const int rA = t >> 3, cA = (t & 7) * 4;      // row [0,32), float-col
  // B: 512 chunks; rows 64B = 4 chunks. 2 chunks/thread.
  const int rB = t >> 2, cB = (t & 3) * 8;      // row [0,64), short-col

  for (int k0 = 0; k0 < DFEAT; k0 += 32) {
    __syncthreads();
#pragma unroll
    for (int q = 0; q < 4; q++)
      async_copy16(Abase + (size_t)(rA + q * 32) * DFEAT + k0 + cA,
                   &As32[(rA + q * 32) * 32 + cA]);
    async_copy16(W1t + (size_t)rB * DFEAT + k0 + cB, &Bs[rB * 32 + cB]);
    async_copy16(W1t + (size_t)(rB + 64) * DFEAT + k0 + cB, &Bs[(rB + 64) * 32 + cB]);
    __syncthreads();

    short8 a[4], b[4];
    const int mrow = lane & 15, kq = (lane >> 4) * 8;
#pragma unroll
    for (int mt = 0; mt < 4; mt++) {
      const float* ap = &As32[(wr + mt * 16 + mrow) * 32 + kq];
      float4 f0 = *(const float4*)ap;
      float4 f1 = *(const float4*)(ap + 4);
      short8 af;
      af[0] = (short)f2bf(f0.x); af[1] = (short)f2bf(f0.y);
      af[2] = (short)f2bf(f0.z); af[3] = (short)f2bf(f0.w);
      af[4] = (short)f2bf(f1.x); af[5] = (short)f2bf(f1.y);
      af[6] = (short)f2bf(f1.z); af[7] = (short)f2bf(f1.w);
      a[mt] = af;
    }
#pragma unroll
    for (int nt = 0; nt < 4; nt++)
      b[nt] = *(const short8*)&Bs[(wc + nt * 16 + mrow) * 32 + kq];
#pragma unroll
    for (int mt = 0; mt < 4; mt++)
#pragma unroll
      for (int nt = 0; nt < 4; nt++)
        acc[mt][nt] = __builtin_amdgcn_mfma_f32_16x16x32_bf16(a[mt], b[nt], acc[mt][nt], 0, 0, 0);
  }

  const float inv = 1.0f / sqrtf(1.0f + 1e-5f);
  const int rq = (lane >> 4) * 4, cn = lane & 15;
#pragma unroll
  for (int nt = 0; nt < 4; nt++) {
    int j = wc + nt * 16 + cn;
    float bj = b1s[j], gj = g1s[j] * inv, bej = be1s[j], wj = wls[j];
#pragma unroll
    for (int mt = 0; mt < 4; mt++) {
#pragma unroll
      for (int rr = 0; rr < 4; rr++) {
        int i_loc = wr + mt * 16 + rq + rr;
        float pre = acc[mt][nt][rr] + sc[i_loc] * wj + bj;
        h1s[i_loc][j] = fmaxf(gj * pre + bej, 0.f);
      }
    }
  }
  __syncthreads();

  // layer 2: 128 -> 64 from LDS. j = t&63, 32 rows per thread.
  {
    int j = t & 63, rg = (t >> 6) * 32;
    float a2[32];
#pragma unroll
    for (int rr = 0; rr < 32; rr++) a2[rr] = 0.f;
    for (int k = 0; k < 128; k++) {
      float w = W2[k * 64 + j];
#pragma unroll
      for (int rr = 0; rr < 32; rr++) a2[rr] += h1s[rg + rr][k] * w;
    }
    float scv = g2[j] * inv, bi = b2[j], be = be2[j];
#pragma unroll
    for (int rr = 0; rr < 32; rr++)
      h2s[rg + rr][j] = fmaxf(scv * (a2[rr] + bi) + be, 0.f);
  }
  __syncthreads();

  // layer 3: 64 -> 1 + sigmoid
  if (t < 128) {
    float z = b3[0];
    for (int k = 0; k < 64; k++) z += h2s[t][k] * W3[k];
    ls[t] = 1.f / (1.f + __expf(-z));
  }
  __syncthreads();
  if (t == 0) {
    float s = 0.f;
#pragma unroll
    for (int i = 0; i < 128; i++) s += ls[i];
    atomicAdd(&sums[1], (double)s);
  }
}

// ---- kernel 4: combine ----
__global__ void finalize(const double* __restrict__ sums, float* __restrict__ out) {
  double simmean = sums[0] / ((double)N_IMG * (double)N_IMG);
  double aggmean = sums[1] / (double)N_IMG;
  out[0] = (float)(aggmean * simmean);
}

extern "C" void kernel_launch(void* const* d_in, const int* in_sizes, int n_in,
                              void* d_out, int out_size, void* d_ws, size_t ws_size,
                              hipStream_t stream) {
  const float* f      = (const float*)d_in[0];
  const float* scores = (const float*)d_in[1];
  const float* W1 = (const float*)d_in[2];
  const float* b1 = (const float*)d_in[3];
  const float* g1 = (const float*)d_in[4];
  const float* be1 = (const float*)d_in[5];
  const float* W2 = (const float*)d_in[6];
  const float* b2 = (const float*)d_in[7];
  const float* g2 = (const float*)d_in[8];
  const float* be2 = (const float*)d_in[9];
  const float* W3 = (const float*)d_in[10];
  const float* b3 = (const float*)d_in[11];

  // workspace layout (9.77 MB total)
  char* ws = (char*)d_ws;
  unsigned char* fb8  = (unsigned char*)ws;                  // 9,437,184 B
  float* sq           = (float*)(ws + 9437184);              // 36,864 B
  float* rn           = (float*)(ws + 9474048);              // 36,864 B
  unsigned short* W1t = (unsigned short*)(ws + 9510912);     // 262,144 B
  double* sums        = (double*)(ws + 9773056);             // 16 B

  prep_w1t<<<128, 256, 0, stream>>>(W1, W1t, sums);
  convert_rows<<<N_IMG, 256, 0, stream>>>(f, fb8, sq, rn);
  mlp_full<<<NB, 256, 0, stream>>>(f, W1t, scores, W1, b1, g1, be1,
                                   W2, b2, g2, be2, W3, b3, sums);
  gram_sim<<<NB * (NB + 1) / 2, 256, 0, stream>>>(fb8, sq, rn, sums);
  finalize<<<1, 1, 0, stream>>>(sums, (float*)d_out);
}

// Round 4
// 218.686 us; speedup vs baseline: 1.8858x; 1.0651x over previous
//
#include <hip/hip_runtime.h>

#define N_IMG 9216
#define DFEAT 1024
#define NB 72            // 9216 / 128 tile blocks per dim

typedef __attribute__((ext_vector_type(8))) short short8;
typedef __attribute__((ext_vector_type(4))) float floatx4;
typedef __attribute__((ext_vector_type(16))) float floatx16;
typedef __attribute__((ext_vector_type(4))) int intx4;
typedef __attribute__((ext_vector_type(8))) int intx8;

__device__ __forceinline__ void async_copy16(const void* g, void* l) {
  __builtin_amdgcn_global_load_lds((const __attribute__((address_space(1))) void*)g,
                                   (__attribute__((address_space(3))) void*)l,
                                   16, 0, 0);
}

__device__ __forceinline__ unsigned short f2bf(float x) {
  union { float f; unsigned u; } a; a.f = x;
  unsigned u = a.u;
  u += 0x7fffu + ((u >> 16) & 1u);   // round-to-nearest-even
  return (unsigned short)(u >> 16);
}

// load one lane's 32B f8f6f4 fragment (contiguous in tiled layout)
__device__ __forceinline__ intx8 ldfrag(const unsigned char* __restrict__ p) {
  intx8 v;
  *(intx4*)&v = *(const intx4*)p;
  ((intx4*)&v)[1] = *(const intx4*)(p + 16);
  return v;
}

// ---- kernel 1: fp32 -> fp8(e4m3) in FRAGMENT-TILED layout + norms; also W1^T bf16 ----
// tiled layout: fbT[rt][kb][r][64B], rt = row>>5 (288), kb = k>>6 (16), r = row&31.
// fragment for (rt,kb): lane(r,kh) reads 32B at (rt*16+kb)*2048 + r*64 + kh*32.
__global__ __launch_bounds__(256) void convert_prep(const float* __restrict__ f,
                                                    const float* __restrict__ W1,
                                                    unsigned char* __restrict__ fbT,
                                                    float* __restrict__ sq,
                                                    float* __restrict__ rn,
                                                    unsigned short* __restrict__ W1t,
                                                    double* __restrict__ sums) {
  int b = blockIdx.x, t = threadIdx.x;
  if (b < 2304) {
    int lane = t & 63, wave = t >> 6;
    int row = b * 4 + wave;                      // one wave per row
    const float4* src = (const float4*)f + (size_t)row * 256;
    unsigned char* tb = fbT + (size_t)(row >> 5) * 32768 + (row & 31) * 64;
    float s = 0.f;
#pragma unroll
    for (int j = 0; j < 4; j++) {
      float4 v = src[j * 64 + lane];             // floats k = j*256 + lane*4 ..
      s += v.x * v.x + v.y * v.y + v.z * v.z + v.w * v.w;
      int pk = __builtin_amdgcn_cvt_pk_fp8_f32(v.x, v.y, 0, false);
      pk = __builtin_amdgcn_cvt_pk_fp8_f32(v.z, v.w, pk, true);
      int kb = j * 4 + (lane >> 4);
      *(unsigned int*)(tb + kb * 2048 + (lane & 15) * 4) = (unsigned int)pk;
    }
#pragma unroll
    for (int off = 32; off > 0; off >>= 1) s += __shfl_down(s, off, 64);
    if (lane == 0) { sq[row] = s; rn[row] = rsqrtf(s); }
  } else {
    int j = b - 2304;                            // 128 blocks: W1 column j -> W1t row j
    if (j == 0 && t < 2) sums[t] = 0.0;
    for (int k = t; k < DFEAT; k += 256)
      W1t[(size_t)j * DFEAT + k] = f2bf(W1[(size_t)k * 128 + j]);
  }
}

// ---- kernel 2: Gram via MX-fp8 MFMA, direct-from-global fragments, NO LDS/barriers ----
// Upper-triangular 128x128 blocks; supertile (8 br-rows) enumeration for L2 locality;
// XCD-swizzle so same-XCD blocks get consecutive logical ids.
__global__ __launch_bounds__(256) void gram_sim(const unsigned char* __restrict__ fbT,
                                                const float* __restrict__ sq,
                                                const float* __restrict__ rn,
                                                double* __restrict__ sums) {
  // XCD swizzle: 2628 = 4*329 + 4*328
  int x = blockIdx.x & 7, i = blockIdx.x >> 3;
  int logical = (x < 4) ? (x * 329 + i) : (4 * 329 + (x - 4) * 328 + i);
  // supertile decode: group g = 8 br rows; within group, bc-major (8 idx share bc)
  int g = 0, rem = logical;
  for (;;) { int cg = 28 + 8 * (65 - 8 * g); if (rem < cg) break; rem -= cg; g++; }
  int br, bc;
  if (rem < 28) {          // ramp: bc = 8g+d has d+1 rows
    int d = 0;
    while (rem >= d + 1) { rem -= d + 1; d++; }
    bc = 8 * g + d; br = 8 * g + rem;
  } else {
    rem -= 28;
    bc = 8 * g + 7 + (rem >> 3);
    br = 8 * g + (rem & 7);
  }

  __shared__ float sqA[128], sqB[128], rnA[128], rnB[128];
  __shared__ float wpart[4];

  int t = threadIdx.x;
  int lane = t & 63, wave = t >> 6;

  if (t < 128) { sqA[t] = sq[br * 128 + t]; rnA[t] = rn[br * 128 + t]; }
  else { sqB[t - 128] = sq[bc * 128 + (t - 128)]; rnB[t - 128] = rn[bc * 128 + (t - 128)]; }
  __syncthreads();

  floatx16 acc[2][2];
#pragma unroll
  for (int a = 0; a < 2; a++)
#pragma unroll
    for (int bq = 0; bq < 2; bq++)
#pragma unroll
      for (int e = 0; e < 16; e++) acc[a][bq][e] = 0.f;

  const int wr = (wave & 1) * 64, wc = (wave >> 1) * 64;
  const int loff = (lane & 31) * 64 + (lane >> 5) * 32;

  const unsigned char* pa0 = fbT + (size_t)(br * 4 + (wr >> 5)) * 32768 + loff;
  const unsigned char* pa1 = pa0 + 32768;
  const unsigned char* pb0 = fbT + (size_t)(bc * 4 + (wc >> 5)) * 32768 + loff;
  const unsigned char* pb1 = pb0 + 32768;

#define MFMA4(A, B)                                                              \
  {                                                                              \
    acc[0][0] = __builtin_amdgcn_mfma_scale_f32_32x32x64_f8f6f4(                 \
        A[0], B[0], acc[0][0], 0, 0, 0, 0x7F7F7F7F, 0, 0x7F7F7F7F);              \
    acc[0][1] = __builtin_amdgcn_mfma_scale_f32_32x32x64_f8f6f4(                 \
        A[0], B[1], acc[0][1], 0, 0, 0, 0x7F7F7F7F, 0, 0x7F7F7F7F);              \
    acc[1][0] = __builtin_amdgcn_mfma_scale_f32_32x32x64_f8f6f4(                 \
        A[1], B[0], acc[1][0], 0, 0, 0, 0x7F7F7F7F, 0, 0x7F7F7F7F);              \
    acc[1][1] = __builtin_amdgcn_mfma_scale_f32_32x32x64_f8f6f4(                 \
        A[1], B[1], acc[1][1], 0, 0, 0, 0x7F7F7F7F, 0, 0x7F7F7F7F);              \
  }

  intx8 aC[2], bC[2], aN[2], bN[2];
  aC[0] = ldfrag(pa0); aC[1] = ldfrag(pa1);
  bC[0] = ldfrag(pb0); bC[1] = ldfrag(pb1);
#pragma unroll
  for (int kb2 = 0; kb2 < 8; kb2++) {
    const int o1 = (kb2 * 2 + 1) * 2048;
    aN[0] = ldfrag(pa0 + o1); aN[1] = ldfrag(pa1 + o1);
    bN[0] = ldfrag(pb0 + o1); bN[1] = ldfrag(pb1 + o1);
    MFMA4(aC, bC);
    if (kb2 < 7) {
      const int o2 = (kb2 * 2 + 2) * 2048;
      aC[0] = ldfrag(pa0 + o2); aC[1] = ldfrag(pa1 + o2);
      bC[0] = ldfrag(pb0 + o2); bC[1] = ldfrag(pb1 + o2);
    }
    MFMA4(aN, bN);
  }
#undef MFMA4

  // epilogue: C/D 32x32 layout col=lane&31, row=(reg&3)+8*(reg>>2)+4*(lane>>5)
  const bool diag = (br == bc);
  const int r = lane & 31, kh = lane >> 5;
  (void)r;
  float lsum = 0.f;
#pragma unroll
  for (int ni = 0; ni < 2; ni++) {
    int j_loc = wc + ni * 32 + (lane & 31);
    float sj = sqB[j_loc], rnj = rnB[j_loc];
#pragma unroll
    for (int mi = 0; mi < 2; mi++) {
      int rbase = wr + mi * 32 + 4 * kh;
#pragma unroll
      for (int reg = 0; reg < 16; reg++) {
        int i_loc = rbase + (reg & 3) + 8 * (reg >> 2);
        float gv = acc[mi][ni][reg];
        float si = sqA[i_loc], rni = rnA[i_loc];
        float cosv = gv * rni * rnj;
        float den = fmaf(1024.f, cosv, 1024.f);    // never near 0 on this data
        float d2 = si + sj - (gv + gv);
        float arg = -d2 * __builtin_amdgcn_rcpf(den);
        float sim = __builtin_amdgcn_exp2f(arg * 1.44269504f);
        if (diag && i_loc == j_loc) sim = 1.f;
        lsum += sim;
      }
    }
  }
#pragma unroll
  for (int off = 32; off > 0; off >>= 1) lsum += __shfl_down(lsum, off, 64);
  if (lane == 0) wpart[wave] = lsum;
  __syncthreads();
  if (t == 0) {
    float tot = (wpart[0] + wpart[1] + wpart[2] + wpart[3]) * (diag ? 1.f : 2.f);
    atomicAdd(&sums[0], (double)tot);
  }
}

// ---- kernel 3: full MLP, 64 rows/block (144 blocks): L1 bf16 MFMA, L2/L3 fp32 in LDS ----
__global__ __launch_bounds__(256) void mlp_full(const float* __restrict__ f,
                                                const unsigned short* __restrict__ W1t,
                                                const float* __restrict__ scores,
                                                const float* __restrict__ W1,
                                                const float* __restrict__ b1,
                                                const float* __restrict__ g1,
                                                const float* __restrict__ be1,
                                                const float* __restrict__ W2, const float* __restrict__ b2,
                                                const float* __restrict__ g2, const float* __restrict__ be2,
                                                const float* __restrict__ W3, const float* __restrict__ b3,
                                                double* __restrict__ sums) {
  int r0 = blockIdx.x * 64;

  __shared__ __align__(16) float As32[64 * 32];         // 8 KB, XOR-swizzled chunks
  __shared__ __align__(16) unsigned short Bs[128 * 32]; // 8 KB, XOR-swizzled chunks
  __shared__ float h1s[64][128];                        // 32 KB
  __shared__ float h2s[64][65];                         // 16.6 KB
  __shared__ float sc[64], b1s[128], g1s[128], be1s[128], wls[128], ls[64];

  int t = threadIdx.x, lane = t & 63, wave = t >> 6;
  if (t < 64) sc[t] = scores[r0 + t];
  if (t < 128) {
    b1s[t] = b1[t]; g1s[t] = g1[t]; be1s[t] = be1[t];
    wls[t] = W1[(size_t)DFEAT * 128 + t];
  }

  floatx4 acc[2][4];
#pragma unroll
  for (int a = 0; a < 2; a++)
#pragma unroll
    for (int b = 0; b < 4; b++) acc[a][b] = (floatx4){0.f, 0.f, 0.f, 0.f};

  const int wr = (wave & 1) * 32, wc = (wave >> 1) * 64;

  for (int k0 = 0; k0 < DFEAT; k0 += 32) {
    __syncthreads();
    {
      // A: 512 chunks (64 rows x 8); phys chunk p of row r holds logical p^(r&7)
      int c = t, rA = c >> 3, p = c & 7, l = p ^ (rA & 7);
      async_copy16(f + (size_t)(r0 + rA) * DFEAT + k0 + l * 4, (char*)As32 + c * 16);
      c = t + 256; rA = c >> 3; p = c & 7; l = p ^ (rA & 7);
      async_copy16(f + (size_t)(r0 + rA) * DFEAT + k0 + l * 4, (char*)As32 + c * 16);
      // B: 512 chunks (128 rows x 4); phys p holds logical p^(r&3)
      c = t; int rB = c >> 2; p = c & 3; l = p ^ (rB & 3);
      async_copy16(W1t + (size_t)rB * DFEAT + k0 + l * 8, (char*)Bs + c * 16);
      c = t + 256; rB = c >> 2; p = c & 3; l = p ^ (rB & 3);
      async_copy16(W1t + (size_t)rB * DFEAT + k0 + l * 8, (char*)Bs + c * 16);
    }
    __syncthreads();

    const int mrow = lane & 15, kq = (lane >> 4) * 8;
    short8 a[2], b[4];
#pragma unroll
    for (int mt = 0; mt < 2; mt++) {
      int row = wr + mt * 16 + mrow;
      int l0 = kq >> 2;
      int p0 = l0 ^ (row & 7), p1 = (l0 + 1) ^ (row & 7);
      float4 f0 = *(const float4*)&As32[row * 32 + p0 * 4];
      float4 f1 = *(const float4*)&As32[row * 32 + p1 * 4];
      short8 af;
      af[0] = (short)f2bf(f0.x); af[1] = (short)f2bf(f0.y);
      af[2] = (short)f2bf(f0.z); af[3] = (short)f2bf(f0.w);
      af[4] = (short)f2bf(f1.x); af[5] = (short)f2bf(f1.y);
      af[6] = (short)f2bf(f1.z); af[7] = (short)f2bf(f1.w);
      a[mt] = af;
    }
#pragma unroll
    for (int nt = 0; nt < 4; nt++) {
      int row = wc + nt * 16 + mrow;
      int p = (kq >> 3) ^ (row & 3);
      b[nt] = *(const short8*)&Bs[row * 32 + p * 8];
    }
#pragma unroll
    for (int mt = 0; mt < 2; mt++)
#pragma unroll
      for (int nt = 0; nt < 4; nt++)
        acc[mt][nt] = __builtin_amdgcn_mfma_f32_16x16x32_bf16(a[mt], b[nt], acc[mt][nt], 0, 0, 0);
  }

  const float inv = 1.0f / sqrtf(1.0f + 1e-5f);
  const int rq = (lane >> 4) * 4, cn = lane & 15;
#pragma unroll
  for (int nt = 0; nt < 4; nt++) {
    int j = wc + nt * 16 + cn;
    float bj = b1s[j], gj = g1s[j] * inv, bej = be1s[j], wj = wls[j];
#pragma unroll
    for (int mt = 0; mt < 2; mt++) {
#pragma unroll
      for (int rr = 0; rr < 4; rr++) {
        int iL = wr + mt * 16 + rq + rr;
        float pre = acc[mt][nt][rr] + sc[iL] * wj + bj;
        h1s[iL][j] = fmaxf(gj * pre + bej, 0.f);
      }
    }
  }
  __syncthreads();

  // layer 2: 128 -> 64. j = t&63, 16 rows/thread (broadcast LDS reads)
  {
    int j = t & 63, rg = (t >> 6) * 16;
    float a2[16];
#pragma unroll
    for (int rr = 0; rr < 16; rr++) a2[rr] = 0.f;
    for (int k = 0; k < 128; k++) {
      float w = W2[k * 64 + j];
#pragma unroll
      for (int rr = 0; rr < 16; rr++) a2[rr] = fmaf(h1s[rg + rr][k], w, a2[rr]);
    }
    float scv = g2[j] * inv, bi = b2[j], be = be2[j];
#pragma unroll
    for (int rr = 0; rr < 16; rr++)
      h2s[rg + rr][j] = fmaxf(scv * (a2[rr] + bi) + be, 0.f);
  }
  __syncthreads();

  // layer 3: 64 -> 1 + sigmoid
  if (t < 64) {
    float z = b3[0];
#pragma unroll
    for (int k = 0; k < 64; k++) z = fmaf(h2s[t][k], W3[k], z);
    ls[t] = 1.f / (1.f + __expf(-z));
  }
  __syncthreads();
  if (t == 0) {
    float s = 0.f;
#pragma unroll
    for (int iL = 0; iL < 64; iL++) s += ls[iL];
    atomicAdd(&sums[1], (double)s);
  }
}

// ---- kernel 4: combine ----
__global__ void finalize(const double* __restrict__ sums, float* __restrict__ out) {
  double simmean = sums[0] / ((double)N_IMG * (double)N_IMG);
  double aggmean = sums[1] / (double)N_IMG;
  out[0] = (float)(aggmean * simmean);
}

extern "C" void kernel_launch(void* const* d_in, const int* in_sizes, int n_in,
                              void* d_out, int out_size, void* d_ws, size_t ws_size,
                              hipStream_t stream) {
  const float* f      = (const float*)d_in[0];
  const float* scores = (const float*)d_in[1];
  const float* W1 = (const float*)d_in[2];
  const float* b1 = (const float*)d_in[3];
  const float* g1 = (const float*)d_in[4];
  const float* be1 = (const float*)d_in[5];
  const float* W2 = (const float*)d_in[6];
  const float* b2 = (const float*)d_in[7];
  const float* g2 = (const float*)d_in[8];
  const float* be2 = (const float*)d_in[9];
  const float* W3 = (const float*)d_in[10];
  const float* b3 = (const float*)d_in[11];

  // workspace layout (9.77 MB total)
  char* ws = (char*)d_ws;
  unsigned char* fbT  = (unsigned char*)ws;                  // 9,437,184 B (tiled fp8)
  float* sq           = (float*)(ws + 9437184);              // 36,864 B
  float* rn           = (float*)(ws + 9474048);              // 36,864 B
  unsigned short* W1t = (unsigned short*)(ws + 9510912);     // 262,144 B
  double* sums        = (double*)(ws + 9773056);             // 16 B

  convert_prep<<<2432, 256, 0, stream>>>(f, W1, fbT, sq, rn, W1t, sums);
  gram_sim<<<NB * (NB + 1) / 2, 256, 0, stream>>>(fbT, sq, rn, sums);
  mlp_full<<<144, 256, 0, stream>>>(f, W1t, scores, W1, b1, g1, be1,
                                    W2, b2, g2, be2, W3, b3, sums);
  finalize<<<1, 1, 0, stream>>>(sums, (float*)d_out);
}

// Round 5
// 204.458 us; speedup vs baseline: 2.0170x; 1.0696x over previous
//
#include <hip/hip_runtime.h>

#define N_IMG 9216
#define DFEAT 1024
#define NBC 36           // 256-col panels
#define NBR 72           // 128-row panels
#define NPAIR 1332       // sum over bcol of min(72, 2*bcol+2)

typedef __attribute__((ext_vector_type(8))) short short8;
typedef __attribute__((ext_vector_type(4))) float floatx4;
typedef __attribute__((ext_vector_type(16))) float floatx16;
typedef __attribute__((ext_vector_type(4))) int intx4;
typedef __attribute__((ext_vector_type(8))) int intx8;

__device__ __forceinline__ void async_copy16(const void* g, void* l) {
  __builtin_amdgcn_global_load_lds((const __attribute__((address_space(1))) void*)g,
                                   (__attribute__((address_space(3))) void*)l,
                                   16, 0, 0);
}

__device__ __forceinline__ unsigned short f2bf(float x) {
  union { float f; unsigned u; } a; a.f = x;
  unsigned u = a.u;
  u += 0x7fffu + ((u >> 16) & 1u);   // round-to-nearest-even
  return (unsigned short)(u >> 16);
}

// staging decode: physical 16B chunk P -> (row, byte-offset) under the
// 2-row / 8-granule XOR swizzle. line=P>>3, pi=P&7, idx=pi^(line&7),
// row=2*line+(idx>>2), chunk-col=idx&3.
__device__ __forceinline__ size_t sw_decode(int P) {
  int L = P >> 3, ix = (P & 7) ^ (L & 7);
  return (size_t)(L * 2 + (ix >> 2)) * DFEAT + (size_t)(ix & 3) * 16;
}

// swizzled LDS 16B read of logical (row r, chunk c)
__device__ __forceinline__ intx4 ld16s(const unsigned char* base, int r, int c) {
  int L = r >> 1, ix = (((r & 1) << 2) | c) ^ (L & 7);
  return *(const intx4*)(base + L * 128 + ix * 16);
}

__device__ __forceinline__ intx8 ldfrags(const unsigned char* base, int r, int kh) {
  intx4 lo = ld16s(base, r, kh * 2);
  intx4 hi = ld16s(base, r, kh * 2 + 1);
  intx8 v;
  v[0] = lo[0]; v[1] = lo[1]; v[2] = lo[2]; v[3] = lo[3];
  v[4] = hi[0]; v[5] = hi[1]; v[6] = hi[2]; v[7] = hi[3];
  return v;
}

// ---- kernel 1: fp32 -> fp8(e4m3) linear rows + norms; also W1^T bf16; init sums ----
__global__ __launch_bounds__(256) void convert_prep(const float* __restrict__ f,
                                                    const float* __restrict__ W1,
                                                    unsigned char* __restrict__ fb8,
                                                    float* __restrict__ sq,
                                                    float* __restrict__ rn,
                                                    unsigned short* __restrict__ W1t,
                                                    double* __restrict__ sums) {
  int b = blockIdx.x, t = threadIdx.x;
  if (b < 2304) {
    int lane = t & 63, wave = t >> 6;
    int row = b * 4 + wave;                      // one wave per row
    const float4* src = (const float4*)f + (size_t)row * 256;
    unsigned int* dst = (unsigned int*)(fb8 + (size_t)row * DFEAT);
    float s = 0.f;
#pragma unroll
    for (int j = 0; j < 4; j++) {
      float4 v = src[j * 64 + lane];
      s += v.x * v.x + v.y * v.y + v.z * v.z + v.w * v.w;
      int pk = __builtin_amdgcn_cvt_pk_fp8_f32(v.x, v.y, 0, false);
      pk = __builtin_amdgcn_cvt_pk_fp8_f32(v.z, v.w, pk, true);
      dst[j * 64 + lane] = (unsigned int)pk;     // coalesced dword stores
    }
#pragma unroll
    for (int off = 32; off > 0; off >>= 1) s += __shfl_down(s, off, 64);
    if (lane == 0) { sq[row] = s; rn[row] = rsqrtf(s); }
  } else {
    int j = b - 2304;                            // W1 column j -> W1t row j
    if (j == 0 && t < 2) sums[t] = 0.0;
    for (int k = t; k < DFEAT; k += 256)
      W1t[(size_t)j * DFEAT + k] = f2bf(W1[(size_t)k * 128 + j]);
  }
}

// ---- kernel 2: Gram via MX-fp8 MFMA, 128x256 tiles, LDS double-buffered ----
__global__ __launch_bounds__(256, 2) void gram_sim(const unsigned char* __restrict__ fb8,
                                                   const float* __restrict__ sq,
                                                   const float* __restrict__ rn,
                                                   double* __restrict__ sums) {
  // decode blockIdx -> (bcol, brow), brow < min(72, 2*bcol+2)
  int rem = blockIdx.x, bcol = 0;
  for (;;) {
    int m = 2 * bcol + 2; if (m > NBR) m = NBR;
    if (rem < m) break;
    rem -= m; bcol++;
  }
  int brow = rem;

  __shared__ __align__(16) unsigned char Ab[2][8192];   // 128 rows x 64 B
  __shared__ __align__(16) unsigned char Bb[2][16384];  // 256 rows x 64 B
  __shared__ float sqA[128], rnA[128], sqB[256], rnB[256];
  __shared__ float wpart[4];

  int t = threadIdx.x, lane = t & 63, wave = t >> 6;
  if (t < 128) { sqA[t] = sq[brow * 128 + t]; rnA[t] = rn[brow * 128 + t]; }
  sqB[t] = sq[bcol * 256 + t];
  rnB[t] = rn[bcol * 256 + t];

  const unsigned char* Asrc = fb8 + (size_t)brow * 128 * DFEAT;
  const unsigned char* Bsrc = fb8 + (size_t)bcol * 256 * DFEAT;

  // per-thread staging source offsets (swizzled), dest is forced lane-contiguous
  const size_t d0 = sw_decode(t);         // A chunk t / B chunk t
  const size_t d1 = sw_decode(t + 256);   // A chunk t+256 / B chunk t+256
  const size_t d2 = sw_decode(t + 512);   // B chunk t+512
  const size_t d3 = sw_decode(t + 768);   // B chunk t+768

  floatx16 acc[2][4];
#pragma unroll
  for (int mi = 0; mi < 2; mi++)
#pragma unroll
    for (int ni = 0; ni < 4; ni++)
#pragma unroll
      for (int e = 0; e < 16; e++) acc[mi][ni][e] = 0.f;

  const int wr = (wave & 1) * 64, wc = (wave >> 1) * 128;
  const int r32 = lane & 31, kh = lane >> 5;

  // prologue: stage k0=0 into buffer 0
  async_copy16(Asrc + d0, &Ab[0][t * 16]);
  async_copy16(Asrc + d1, &Ab[0][(t + 256) * 16]);
  async_copy16(Bsrc + d0, &Bb[0][t * 16]);
  async_copy16(Bsrc + d1, &Bb[0][(t + 256) * 16]);
  async_copy16(Bsrc + d2, &Bb[0][(t + 512) * 16]);
  async_copy16(Bsrc + d3, &Bb[0][(t + 768) * 16]);

  for (int kb = 0; kb < 16; kb++) {
    __syncthreads();                       // drains staging vmcnt; protects prev reads
    if (kb < 15) {
      const int nb = (kb + 1) & 1;
      const size_t k0 = (size_t)(kb + 1) * 64;
      async_copy16(Asrc + d0 + k0, &Ab[nb][t * 16]);
      async_copy16(Asrc + d1 + k0, &Ab[nb][(t + 256) * 16]);
      async_copy16(Bsrc + d0 + k0, &Bb[nb][t * 16]);
      async_copy16(Bsrc + d1 + k0, &Bb[nb][(t + 256) * 16]);
      async_copy16(Bsrc + d2 + k0, &Bb[nb][(t + 512) * 16]);
      async_copy16(Bsrc + d3 + k0, &Bb[nb][(t + 768) * 16]);
    }
    const unsigned char* Ac = Ab[kb & 1];
    const unsigned char* Bc = Bb[kb & 1];
    intx8 a[2], b[4];
#pragma unroll
    for (int mi = 0; mi < 2; mi++) a[mi] = ldfrags(Ac, wr + mi * 32 + r32, kh);
#pragma unroll
    for (int ni = 0; ni < 4; ni++) b[ni] = ldfrags(Bc, wc + ni * 32 + r32, kh);
#pragma unroll
    for (int mi = 0; mi < 2; mi++)
#pragma unroll
      for (int ni = 0; ni < 4; ni++)
        acc[mi][ni] = __builtin_amdgcn_mfma_scale_f32_32x32x64_f8f6f4(
            a[mi], b[ni], acc[mi][ni], 0, 0, 0, 0x7F7F7F7F, 0, 0x7F7F7F7F);
  }

  // epilogue: C/D 32x32 layout col=lane&31, row=(reg&3)+8*(reg>>2)+4*(lane>>5)
  const bool interior = (brow < 2 * bcol);   // whole tile strictly above diagonal
  float lsum = 0.f;
#pragma unroll
  for (int ni = 0; ni < 4; ni++) {
    int j_loc = wc + ni * 32 + r32;
    float sj = sqB[j_loc], rnj = rnB[j_loc];
    int j_g = bcol * 256 + j_loc;
#pragma unroll
    for (int mi = 0; mi < 2; mi++) {
      int rbase = wr + mi * 32 + 4 * kh;
#pragma unroll
      for (int reg = 0; reg < 16; reg++) {
        int i_loc = rbase + (reg & 3) + 8 * (reg >> 2);
        float gv = acc[mi][ni][reg];
        float si = sqA[i_loc], rni = rnA[i_loc];
        float cosv = gv * rni * rnj;
        float den = fmaf(1024.f, cosv, 1024.f);   // never near 0 on this data
        float d2 = si + sj - (gv + gv);
        float sim = __builtin_amdgcn_exp2f(-d2 * __builtin_amdgcn_rcpf(den) * 1.44269504f);
        if (interior) {
          lsum += sim;
        } else {
          int i_g = brow * 128 + i_loc;
          lsum += (i_g < j_g) ? 2.f * sim : (i_g == j_g ? 1.f : 0.f);
        }
      }
    }
  }
  if (interior) lsum *= 2.f;
#pragma unroll
  for (int off = 32; off > 0; off >>= 1) lsum += __shfl_down(lsum, off, 64);
  if (lane == 0) wpart[wave] = lsum;
  __syncthreads();
  if (t == 0)
    atomicAdd(&sums[0], (double)(wpart[0] + wpart[1] + wpart[2] + wpart[3]));
}

// ---- kernel 3: full MLP, 64 rows/block (144 blocks): L1 bf16 MFMA, L2/L3 fp32 in LDS ----
__global__ __launch_bounds__(256) void mlp_full(const float* __restrict__ f,
                                                const unsigned short* __restrict__ W1t,
                                                const float* __restrict__ scores,
                                                const float* __restrict__ W1,
                                                const float* __restrict__ b1,
                                                const float* __restrict__ g1,
                                                const float* __restrict__ be1,
                                                const float* __restrict__ W2, const float* __restrict__ b2,
                                                const float* __restrict__ g2, const float* __restrict__ be2,
                                                const float* __restrict__ W3, const float* __restrict__ b3,
                                                double* __restrict__ sums) {
  int r0 = blockIdx.x * 64;

  __shared__ __align__(16) float As32[64 * 32];         // 8 KB, XOR-swizzled chunks
  __shared__ __align__(16) unsigned short Bs[128 * 32]; // 8 KB, XOR-swizzled chunks
  __shared__ float h1s[64][128];                        // 32 KB
  __shared__ float h2s[64][65];                         // 16.6 KB
  __shared__ float sc[64], b1s[128], g1s[128], be1s[128], wls[128], ls[64];

  int t = threadIdx.x, lane = t & 63, wave = t >> 6;
  if (t < 64) sc[t] = scores[r0 + t];
  if (t < 128) {
    b1s[t] = b1[t]; g1s[t] = g1[t]; be1s[t] = be1[t];
    wls[t] = W1[(size_t)DFEAT * 128 + t];
  }

  floatx4 acc[2][4];
#pragma unroll
  for (int a = 0; a < 2; a++)
#pragma unroll
    for (int b = 0; b < 4; b++) acc[a][b] = (floatx4){0.f, 0.f, 0.f, 0.f};

  const int wr = (wave & 1) * 32, wc = (wave >> 1) * 64;

  for (int k0 = 0; k0 < DFEAT; k0 += 32) {
    __syncthreads();
    {
      // A: 512 chunks (64 rows x 8); phys chunk p of row r holds logical p^(r&7)
      int c = t, rA = c >> 3, p = c & 7, l = p ^ (rA & 7);
      async_copy16(f + (size_t)(r0 + rA) * DFEAT + k0 + l * 4, (char*)As32 + c * 16);
      c = t + 256; rA = c >> 3; p = c & 7; l = p ^ (rA & 7);
      async_copy16(f + (size_t)(r0 + rA) * DFEAT + k0 + l * 4, (char*)As32 + c * 16);
      // B: 512 chunks (128 rows x 4); phys p holds logical p^(r&3)
      c = t; int rB = c >> 2; p = c & 3; l = p ^ (rB & 3);
      async_copy16(W1t + (size_t)rB * DFEAT + k0 + l * 8, (char*)Bs + c * 16);
      c = t + 256; rB = c >> 2; p = c & 3; l = p ^ (rB & 3);
      async_copy16(W1t + (size_t)rB * DFEAT + k0 + l * 8, (char*)Bs + c * 16);
    }
    __syncthreads();

    const int mrow = lane & 15, kq = (lane >> 4) * 8;
    short8 a[2], b[4];
#pragma unroll
    for (int mt = 0; mt < 2; mt++) {
      int row = wr + mt * 16 + mrow;
      int l0 = kq >> 2;
      int p0 = l0 ^ (row & 7), p1 = (l0 + 1) ^ (row & 7);
      float4 f0 = *(const float4*)&As32[row * 32 + p0 * 4];
      float4 f1 = *(const float4*)&As32[row * 32 + p1 * 4];
      short8 af;
      af[0] = (short)f2bf(f0.x); af[1] = (short)f2bf(f0.y);
      af[2] = (short)f2bf(f0.z); af[3] = (short)f2bf(f0.w);
      af[4] = (short)f2bf(f1.x); af[5] = (short)f2bf(f1.y);
      af[6] = (short)f2bf(f1.z); af[7] = (short)f2bf(f1.w);
      a[mt] = af;
    }
#pragma unroll
    for (int nt = 0; nt < 4; nt++) {
      int row = wc + nt * 16 + mrow;
      int p = (kq >> 3) ^ (row & 3);
      b[nt] = *(const short8*)&Bs[row * 32 + p * 8];
    }
#pragma unroll
    for (int mt = 0; mt < 2; mt++)
#pragma unroll
      for (int nt = 0; nt < 4; nt++)
        acc[mt][nt] = __builtin_amdgcn_mfma_f32_16x16x32_bf16(a[mt], b[nt], acc[mt][nt], 0, 0, 0);
  }

  const float inv = 1.0f / sqrtf(1.0f + 1e-5f);
  const int rq = (lane >> 4) * 4, cn = lane & 15;
#pragma unroll
  for (int nt = 0; nt < 4; nt++) {
    int j = wc + nt * 16 + cn;
    float bj = b1s[j], gj = g1s[j] * inv, bej = be1s[j], wj = wls[j];
#pragma unroll
    for (int mt = 0; mt < 2; mt++) {
#pragma unroll
      for (int rr = 0; rr < 4; rr++) {
        int iL = wr + mt * 16 + rq + rr;
        float pre = acc[mt][nt][rr] + sc[iL] * wj + bj;
        h1s[iL][j] = fmaxf(gj * pre + bej, 0.f);
      }
    }
  }
  __syncthreads();

  // layer 2: 128 -> 64. j = t&63, 16 rows/thread (broadcast LDS reads)
  {
    int j = t & 63, rg = (t >> 6) * 16;
    float a2[16];
#pragma unroll
    for (int rr = 0; rr < 16; rr++) a2[rr] = 0.f;
    for (int k = 0; k < 128; k++) {
      float w = W2[k * 64 + j];
#pragma unroll
      for (int rr = 0; rr < 16; rr++) a2[rr] = fmaf(h1s[rg + rr][k], w, a2[rr]);
    }
    float scv = g2[j] * inv, bi = b2[j], be = be2[j];
#pragma unroll
    for (int rr = 0; rr < 16; rr++)
      h2s[rg + rr][j] = fmaxf(scv * (a2[rr] + bi) + be, 0.f);
  }
  __syncthreads();

  // layer 3: 64 -> 1 + sigmoid
  if (t < 64) {
    float z = b3[0];
#pragma unroll
    for (int k = 0; k < 64; k++) z = fmaf(h2s[t][k], W3[k], z);
    ls[t] = 1.f / (1.f + __expf(-z));
  }
  __syncthreads();
  if (t == 0) {
    float s = 0.f;
#pragma unroll
    for (int iL = 0; iL < 64; iL++) s += ls[iL];
    atomicAdd(&sums[1], (double)s);
  }
}

// ---- kernel 4: combine ----
__global__ void finalize(const double* __restrict__ sums, float* __restrict__ out) {
  double simmean = sums[0] / ((double)N_IMG * (double)N_IMG);
  double aggmean = sums[1] / (double)N_IMG;
  out[0] = (float)(aggmean * simmean);
}

extern "C" void kernel_launch(void* const* d_in, const int* in_sizes, int n_in,
                              void* d_out, int out_size, void* d_ws, size_t ws_size,
                              hipStream_t stream) {
  const float* f      = (const float*)d_in[0];
  const float* scores = (const float*)d_in[1];
  const float* W1 = (const float*)d_in[2];
  const float* b1 = (const float*)d_in[3];
  const float* g1 = (const float*)d_in[4];
  const float* be1 = (const float*)d_in[5];
  const float* W2 = (const float*)d_in[6];
  const float* b2 = (const float*)d_in[7];
  const float* g2 = (const float*)d_in[8];
  const float* be2 = (const float*)d_in[9];
  const float* W3 = (const float*)d_in[10];
  const float* b3 = (const float*)d_in[11];

  // workspace layout (9.77 MB total)
  char* ws = (char*)d_ws;
  unsigned char* fb8  = (unsigned char*)ws;                  // 9,437,184 B (linear fp8)
  float* sq           = (float*)(ws + 9437184);              // 36,864 B
  float* rn           = (float*)(ws + 9474048);              // 36,864 B
  unsigned short* W1t = (unsigned short*)(ws + 9510912);     // 262,144 B
  double* sums        = (double*)(ws + 9773056);             // 16 B

  convert_prep<<<2432, 256, 0, stream>>>(f, W1, fb8, sq, rn, W1t, sums);
  gram_sim<<<NPAIR, 256, 0, stream>>>(fb8, sq, rn, sums);
  mlp_full<<<144, 256, 0, stream>>>(f, W1t, scores, W1, b1, g1, be1,
                                    W2, b2, g2, be2, W3, b3, sums);
  finalize<<<1, 1, 0, stream>>>(sums, (float*)d_out);
}